// Round 1
// baseline (193.113 us; speedup 1.0000x reference)
//
#include <hip/hip_runtime.h>
#include <math.h>

#define BLOCKS  2048
#define THREADS 256

static constexpr float PI_F     = 3.14159265358979323846f;
static constexpr float TWO_PI_F = 6.28318530717958647692f;

// ---------------------------------------------------------------------------
// The fused pointwise transform (everything between the two normalizations).
// theta = -pi + 2*pi*sigmoid(x)   (exact closed form of the linspace lerp)
// ds    = 3 * |tanh(x)|           (exact closed form of the linspace lerp)
// y     = x * exp(ds*sin(theta)) + ds*cos(theta)
// ---------------------------------------------------------------------------
__device__ __forceinline__ float transform(float d, float mean1, float scale1) {
    float x  = (d - mean1) * scale1;            // scale1 = iscale / std1
    float sg = 1.0f / (1.0f + expf(-x));        // sigmoid
    float theta = fmaf(sg, TWO_PI_F, -PI_F);
    float ds = 3.0f * fabsf(tanhf(x));
    float sn, cs;
    sincosf(theta, &sn, &cs);
    float dy = ds * sn;
    float dx = ds * cs;
    return fmaf(x, expf(dy), dx);
}

// Block-level {sum, sumsq} reduction in double. Result valid in thread 0.
__device__ __forceinline__ void block_reduce2(double& s, double& ss) {
    for (int o = 32; o > 0; o >>= 1) {
        s  += __shfl_down(s,  o);
        ss += __shfl_down(ss, o);
    }
    __shared__ double ls[4], lss[4];
    const int wave = threadIdx.x >> 6;
    const int lane = threadIdx.x & 63;
    if (lane == 0) { ls[wave] = s; lss[wave] = ss; }
    __syncthreads();
    if (threadIdx.x == 0) {
        s = ls[0]; ss = lss[0];
        #pragma unroll
        for (int w = 1; w < THREADS / 64; ++w) { s += ls[w]; ss += lss[w]; }
    }
}

// Pass 1: per-block partial {sum, sumsq} of raw data.
__global__ __launch_bounds__(THREADS) void k_stats1(
        const float4* __restrict__ in, double* __restrict__ part, int n4) {
    double s = 0.0, ss = 0.0;
    const int stride = gridDim.x * blockDim.x;
    for (int i = blockIdx.x * blockDim.x + threadIdx.x; i < n4; i += stride) {
        float4 v = in[i];
        s  += ((double)v.x + (double)v.y) + ((double)v.z + (double)v.w);
        ss += ((double)v.x * v.x + (double)v.y * v.y)
            + ((double)v.z * v.z + (double)v.w * v.w);
    }
    block_reduce2(s, ss);
    if (threadIdx.x == 0) {
        part[2 * blockIdx.x]     = s;
        part[2 * blockIdx.x + 1] = ss;
    }
}

// Finalize pass 1: params[0] = mean1, params[1] = iscale/std1 (ddof=1).
__global__ __launch_bounds__(THREADS) void k_fin1(
        const double* __restrict__ part, float* __restrict__ params,
        const float* __restrict__ iscale, int n) {
    double s = 0.0, ss = 0.0;
    for (int i = threadIdx.x; i < BLOCKS; i += blockDim.x) {
        s += part[2 * i]; ss += part[2 * i + 1];
    }
    block_reduce2(s, ss);
    if (threadIdx.x == 0) {
        double dn   = (double)n;
        double mean = s / dn;
        double var  = (ss - s * s / dn) / (dn - 1.0);
        params[0] = (float)mean;
        params[1] = (float)((1.0 / sqrt(var)) * (double)iscale[0]);
    }
}

// Pass 2: per-block partial {sum, sumsq} of transformed y (recomputed).
__global__ __launch_bounds__(THREADS) void k_stats2(
        const float4* __restrict__ in, double* __restrict__ part,
        const float* __restrict__ params, int n4) {
    const float mean1  = params[0];
    const float scale1 = params[1];
    double s = 0.0, ss = 0.0;
    const int stride = gridDim.x * blockDim.x;
    for (int i = blockIdx.x * blockDim.x + threadIdx.x; i < n4; i += stride) {
        float4 v = in[i];
        float y0 = transform(v.x, mean1, scale1);
        float y1 = transform(v.y, mean1, scale1);
        float y2 = transform(v.z, mean1, scale1);
        float y3 = transform(v.w, mean1, scale1);
        s  += ((double)y0 + (double)y1) + ((double)y2 + (double)y3);
        ss += ((double)y0 * y0 + (double)y1 * y1)
            + ((double)y2 * y2 + (double)y3 * y3);
    }
    block_reduce2(s, ss);
    if (threadIdx.x == 0) {
        part[2 * blockIdx.x]     = s;
        part[2 * blockIdx.x + 1] = ss;
    }
}

// Finalize pass 2: params[2] = oscale/std2, params[3] = -mean2 * params[2].
__global__ __launch_bounds__(THREADS) void k_fin2(
        const double* __restrict__ part, float* __restrict__ params,
        const float* __restrict__ oscale, int n) {
    double s = 0.0, ss = 0.0;
    for (int i = threadIdx.x; i < BLOCKS; i += blockDim.x) {
        s += part[2 * i]; ss += part[2 * i + 1];
    }
    block_reduce2(s, ss);
    if (threadIdx.x == 0) {
        double dn   = (double)n;
        double mean = s / dn;
        double var  = (ss - s * s / dn) / (dn - 1.0);
        double sc   = (1.0 / sqrt(var)) * (double)oscale[0];
        params[2] = (float)sc;
        params[3] = (float)(-mean * sc);
    }
}

// Pass 3: out = y * params[2] + params[3].
__global__ __launch_bounds__(THREADS) void k_final(
        const float4* __restrict__ in, float4* __restrict__ out,
        const float* __restrict__ params, int n4) {
    const float mean1  = params[0];
    const float scale1 = params[1];
    const float a      = params[2];
    const float b      = params[3];
    const int stride = gridDim.x * blockDim.x;
    for (int i = blockIdx.x * blockDim.x + threadIdx.x; i < n4; i += stride) {
        float4 v = in[i];
        float4 r;
        r.x = fmaf(transform(v.x, mean1, scale1), a, b);
        r.y = fmaf(transform(v.y, mean1, scale1), a, b);
        r.z = fmaf(transform(v.z, mean1, scale1), a, b);
        r.w = fmaf(transform(v.w, mean1, scale1), a, b);
        out[i] = r;
    }
}

extern "C" void kernel_launch(void* const* d_in, const int* in_sizes, int n_in,
                              void* d_out, int out_size, void* d_ws, size_t ws_size,
                              hipStream_t stream) {
    const float*  data   = (const float*)d_in[0];
    const float*  iscale = (const float*)d_in[1];
    const float*  oscale = (const float*)d_in[2];
    // d_in[3] (weight) is mathematically irrelevant: softmax rows sum to 1,
    // so _integral(param, idx, sm) == param[idx].
    float* out = (float*)d_out;

    const int n  = in_sizes[0];      // 33554432 = 2^25, divisible by 4
    const int n4 = n / 4;

    double* part   = (double*)d_ws;                               // BLOCKS*2 doubles
    float*  params = (float*)((char*)d_ws + BLOCKS * 2 * sizeof(double)); // 4 floats

    k_stats1<<<BLOCKS, THREADS, 0, stream>>>((const float4*)data, part, n4);
    k_fin1  <<<1,      THREADS, 0, stream>>>(part, params, iscale, n);
    k_stats2<<<BLOCKS, THREADS, 0, stream>>>((const float4*)data, part, params, n4);
    k_fin2  <<<1,      THREADS, 0, stream>>>(part, params, oscale, n);
    k_final <<<BLOCKS, THREADS, 0, stream>>>((const float4*)data, (float4*)out, params, n4);
}